// Round 5
// baseline (452.010 us; speedup 1.0000x reference)
//
#include <hip/hip_runtime.h>
#include <stdint.h>

typedef unsigned short u16;
typedef unsigned int u32;

typedef __bf16 bf8 __attribute__((ext_vector_type(8)));
typedef bf8 bf8a __attribute__((may_alias));
typedef float f32x4 __attribute__((ext_vector_type(4)));
typedef uint2 uint2a __attribute__((may_alias));
typedef ushort4 ushort4a __attribute__((may_alias));
typedef float4 float4a __attribute__((may_alias));

#define MFMA_BF16(a, b, c) __builtin_amdgcn_mfma_f32_16x16x32_bf16((a), (b), (c), 0, 0, 0)

__device__ __forceinline__ u16 f2b(float x) {
  u32 u = __float_as_uint(x);
  return (u16)((u + 0x7fffu + ((u >> 16) & 1u)) >> 16);  // RNE
}
__device__ __forceinline__ u32 pack2(float a, float b) {  // two non-negative f32 -> packed bf16x2
  u32 ua = __float_as_uint(a), ub = __float_as_uint(b);
  return ((ua + 0x8000u) >> 16) | ((ub + 0x8000u) & 0xffff0000u);
}
__device__ __forceinline__ void async16(const u16* g, void* l) {
  __builtin_amdgcn_global_load_lds((const __attribute__((address_space(1))) u32*)g,
                                   (__attribute__((address_space(3))) u32*)l, 16, 0, 0);
}

// ---------------------------------------------------------------------------
// src convert: fp32 [4096][1024] -> bf16 same layout. 1 float4 per thread.
// ---------------------------------------------------------------------------
__global__ __launch_bounds__(256) void convert_src(const float* __restrict__ src,
                                                   u16* __restrict__ dst) {
  const int i = blockIdx.x * 256 + threadIdx.x;  // float4 index
  float4 v = *(const float4a*)(src + i * 4);
  ushort4 o;
  o.x = f2b(v.x); o.y = f2b(v.y); o.z = f2b(v.z); o.w = f2b(v.w);
  *(ushort4a*)(dst + i * 4) = o;
}

// ---------------------------------------------------------------------------
// Weight transpose+convert: w fp32 [K=1024][N=1024] -> wT bf16 [N][K]
// ---------------------------------------------------------------------------
__global__ __launch_bounds__(256) void transpose4(
    const float* __restrict__ w0, const float* __restrict__ w1,
    const float* __restrict__ w2, const float* __restrict__ w3,
    u16* __restrict__ t0, u16* __restrict__ t1, u16* __restrict__ t2, u16* __restrict__ t3) {
  const int z = blockIdx.z;
  const float* W = z == 0 ? w0 : z == 1 ? w1 : z == 2 ? w2 : w3;
  u16* T = z == 0 ? t0 : z == 1 ? t1 : z == 2 ? t2 : t3;
  __shared__ __align__(8) u16 tile[64][68];
  const int tid = threadIdx.x;
  const int ty = tid >> 4, tx = tid & 15;
  const int kb = blockIdx.y * 64, nb = blockIdx.x * 64;
#pragma unroll
  for (int i = 0; i < 4; ++i) {
    int lk = ty + i * 16;
    float4 v = *(const float4a*)(W + (kb + lk) * 1024 + nb + tx * 4);
    ushort4 h;
    h.x = f2b(v.x); h.y = f2b(v.y); h.z = f2b(v.z); h.w = f2b(v.w);
    *(ushort4a*)&tile[lk][tx * 4] = h;
  }
  __syncthreads();
#pragma unroll
  for (int i = 0; i < 4; ++i) {
    int ln = ty + i * 16;
    ushort4 v;
    v.x = tile[tx * 4 + 0][ln];
    v.y = tile[tx * 4 + 1][ln];
    v.z = tile[tx * 4 + 2][ln];
    v.w = tile[tx * 4 + 3][ln];
    *(ushort4a*)(T + (nb + ln) * 1024 + kb + tx * 4) = v;
  }
}

// ---------------------------------------------------------------------------
// GEMM: C[M][N] = A[M,1024] * Bt[N,1024]^T + bias[n]   (m97 structure)
// A, Bt bf16; bias fp32. block 256 = 4 waves (2x2), tile 128x128, BK=32.
// plain=1: write float Of[rm*1024+col] (final out-proj).
// plain=0: z<2 -> bf16 Q/K layout [pair][s][64]; z==2 -> bf16 V^T [pair][e][s].
// (identical to round-3 passing version)
// ---------------------------------------------------------------------------
__global__ __launch_bounds__(256) void gemm_bt(
    const u16* __restrict__ A,
    const u16* __restrict__ B0, const u16* __restrict__ B1, const u16* __restrict__ B2,
    const float* __restrict__ c0, const float* __restrict__ c1, const float* __restrict__ c2,
    u16* __restrict__ O0, u16* __restrict__ O1, u16* __restrict__ O2,
    float* __restrict__ Of, int plain) {
  __shared__ __align__(16) u16 sm[8192];
  u16* As = sm;
  u16* Bs = sm + 4096;
  const int tid = threadIdx.x, lane = tid & 63, w = tid >> 6;
  const int wm = w >> 1, wn = w & 1, quad = lane >> 4, l16 = lane & 15;
  const int z = blockIdx.z;
  const u16* Bt = z == 0 ? B0 : (z == 1 ? B1 : B2);
  const float* bi = z == 0 ? c0 : (z == 1 ? c1 : c2);
  u16* O = z == 0 ? O0 : (z == 1 ? O1 : O2);
  const int row0 = blockIdx.y * 128, col0 = blockIdx.x * 128;

  f32x4 acc[4][4];
#pragma unroll
  for (int i = 0; i < 4; ++i)
#pragma unroll
    for (int j = 0; j < 4; ++j) acc[i][j] = f32x4{0.f, 0.f, 0.f, 0.f};

  const int e0 = tid, e1 = tid + 256;
  const int r0 = e0 >> 2, cc0 = (e0 & 3) * 8;
  const int r1 = e1 >> 2, cc1 = (e1 & 3) * 8;
  const u32 lb0 = (u32)(w * 64) * 16;
  const u32 lb1 = (u32)(w * 64 + 256) * 16;

  for (int k0 = 0; k0 < 1024; k0 += 32) {
    __syncthreads();
    async16(A + (row0 + r0) * 1024 + k0 + cc0, (char*)As + lb0);
    async16(A + (row0 + r1) * 1024 + k0 + cc1, (char*)As + lb1);
    async16(Bt + (col0 + r0) * 1024 + k0 + cc0, (char*)Bs + lb0);
    async16(Bt + (col0 + r1) * 1024 + k0 + cc1, (char*)Bs + lb1);
    __syncthreads();
    bf8a af[4], bfr[4];
#pragma unroll
    for (int i = 0; i < 4; ++i) {
      af[i] = *(const bf8a*)(As + (wm * 64 + i * 16 + l16) * 32 + quad * 8);
      bfr[i] = *(const bf8a*)(Bs + (wn * 64 + i * 16 + l16) * 32 + quad * 8);
    }
#pragma unroll
    for (int mt = 0; mt < 4; ++mt)
#pragma unroll
      for (int nt = 0; nt < 4; ++nt) acc[mt][nt] = MFMA_BF16(af[mt], bfr[nt], acc[mt][nt]);
  }

#pragma unroll
  for (int nt = 0; nt < 4; ++nt) {
    const int col = col0 + wn * 64 + nt * 16 + l16;
    const float bcol = bi[col];
#pragma unroll
    for (int mt = 0; mt < 4; ++mt) {
#pragma unroll
      for (int r = 0; r < 4; ++r) {
        const int rm = row0 + wm * 64 + mt * 16 + quad * 4 + r;
        const float fv = acc[mt][nt][r] + bcol;
        if (plain) {
          Of[rm * 1024 + col] = fv;
        } else {
          const u16 hv = f2b(fv);
          const int s = rm >> 1, b_ = rm & 1, hh = col >> 6, e = col & 63;
          const int p = b_ * 16 + hh;
          if (z < 2) O[(p * 2048 + s) * 64 + e] = hv;  // [pair][s][64]
          else O[(p * 64 + e) * 2048 + s] = hv;        // [pair][e][s] (V^T)
        }
      }
    }
  }
}

// ---------------------------------------------------------------------------
// Flash attention v5 = round-3 mechanics, re-tiled to 16 q-rows per wave.
// One block (4 waves) per (pair, 64-row q-tile); grid (pair=32, qt=32) =
// 1024 blocks = 4096 waves -> 16 waves/CU reachable (was 8).
// S^T = K*Q^T (s on lane&15); padded-136 LDS P round-trip (within-wave);
// shfl broadcasts for alpha/linv; c1 scaling in-kernel. No __syncthreads.
// ---------------------------------------------------------------------------
__global__ __launch_bounds__(256, 4) void attn_fused(
    const u16* __restrict__ Qw, const u16* __restrict__ Kw, const u16* __restrict__ Vw,
    const float* __restrict__ EB, u16* __restrict__ Ao) {
  __shared__ __align__(16) u16 Ps[64 * 136];  // [64 s][128 t], pad 8
  const int tid = threadIdx.x, lane = tid & 63, w = tid >> 6;
  const int quad = lane >> 4, l16 = lane & 15;
  const int pair = blockIdx.x, qt = blockIdx.y;
  const int bb = pair >> 4, hh = pair & 15;
  const u16* Qp = Qw + pair * (2048 * 64);
  const u16* Kp = Kw + pair * (2048 * 64);
  const u16* Vp = Vw + pair * (64 * 2048);
  const int s0 = qt * 64 + w * 16;  // wave's 16-row s strip (global)
  const int prow = w * 16 + l16;    // LDS P row

  bf8a qf[2];  // B-operand (Q^T) frags: n = s, k = d
#pragma unroll
  for (int ks = 0; ks < 2; ++ks)
    qf[ks] = *(const bf8a*)(Qp + (s0 + l16) * 64 + ks * 32 + quad * 8);

  f32x4 oacc[4];
#pragma unroll
  for (int j = 0; j < 4; ++j) oacc[j] = f32x4{0.f, 0.f, 0.f, 0.f};
  float m_s = -1e30f, l_s = 0.f;
  const float c1 = 0.125f * 1.44269504088896340736f;  // scale * log2(e)
  const float c2 = 1.44269504088896340736f;

  for (int kt = 0; kt < 16; ++kt) {
    // S^T = K * Q^T : D[row=t][col=s]
    f32x4 sacc[8];
#pragma unroll
    for (int tt = 0; tt < 8; ++tt) {
      const u16* kr = Kp + (kt * 128 + tt * 16 + l16) * 64 + quad * 8;
      bf8a k0 = *(const bf8a*)kr;
      bf8a k1 = *(const bf8a*)(kr + 32);
      f32x4 t0 = f32x4{0.f, 0.f, 0.f, 0.f};
      t0 = MFMA_BF16(k0, qf[0], t0);
      sacc[tt] = MFMA_BF16(k1, qf[1], t0);
    }
    // z = (qk*scale + bias) * log2e; remember bf16 sign masks for the gate
    u32 sg01[8], sg23[8];
#pragma unroll
    for (int tt = 0; tt < 8; ++tt) {
      const float4 b = *(const float4a*)(EB + (s0 + l16) * 2048 + kt * 128 + tt * 16 + quad * 4);
      sacc[tt][0] = sacc[tt][0] * c1 + b.x * c2;
      sacc[tt][1] = sacc[tt][1] * c1 + b.y * c2;
      sacc[tt][2] = sacc[tt][2] * c1 + b.z * c2;
      sacc[tt][3] = sacc[tt][3] * c1 + b.w * c2;
      sg01[tt] = ((__float_as_uint(b.x) >> 16) & 0x8000u) | (__float_as_uint(b.y) & 0x80000000u);
      sg23[tt] = ((__float_as_uint(b.z) >> 16) & 0x8000u) | (__float_as_uint(b.w) & 0x80000000u);
    }
    // row (s) max: local over t + cross-quad shfl
    float m = -1e30f;
#pragma unroll
    for (int tt = 0; tt < 8; ++tt) {
      m = fmaxf(m, fmaxf(fmaxf(sacc[tt][0], sacc[tt][1]), fmaxf(sacc[tt][2], sacc[tt][3])));
    }
    m = fmaxf(m, __shfl_xor(m, 16));
    m = fmaxf(m, __shfl_xor(m, 32));
    const float mn = fmaxf(m_s, m);
    const float alpha = exp2f(m_s - mn);
    m_s = mn;
    // p = exp2(z - m); pack bf16 pairs with the sign gate
    u32 pd[8][2];
    float lsum = 0.f;
#pragma unroll
    for (int tt = 0; tt < 8; ++tt) {
      const float p0 = exp2f(sacc[tt][0] - m_s);
      const float p1 = exp2f(sacc[tt][1] - m_s);
      const float p2 = exp2f(sacc[tt][2] - m_s);
      const float p3 = exp2f(sacc[tt][3] - m_s);
      lsum += (p0 + p1) + (p2 + p3);
      pd[tt][0] = pack2(p0, p1) | sg01[tt];
      pd[tt][1] = pack2(p2, p3) | sg23[tt];
    }
    lsum += __shfl_xor(lsum, 16);
    lsum += __shfl_xor(lsum, 32);
    l_s = l_s * alpha + lsum;
    // P -> LDS (C-layout write, vectorized b64; within-wave region only)
#pragma unroll
    for (int tt = 0; tt < 8; ++tt) {
      uint2 v;
      v.x = pd[tt][0];
      v.y = pd[tt][1];
      *(uint2a*)((char*)Ps + (prow * 136 + tt * 16 + quad * 4) * 2) = v;
    }
    // O *= alpha (broadcast per O-row via shfl)
    float ar[4];
#pragma unroll
    for (int r = 0; r < 4; ++r) ar[r] = __shfl(alpha, quad * 4 + r);
#pragma unroll
    for (int nt = 0; nt < 4; ++nt)
#pragma unroll
      for (int r = 0; r < 4; ++r) oacc[nt][r] *= ar[r];
    // PV: A = P (from LDS, A-layout b128 reads), B = V^T rows (contiguous t)
#pragma unroll
    for (int kss = 0; kss < 4; ++kss) {
      bf8a pf = *(const bf8a*)((char*)Ps + (prow * 136 + kss * 32 + quad * 8) * 2);
#pragma unroll
      for (int nt = 0; nt < 4; ++nt) {
        bf8a vf = *(const bf8a*)(Vp + (nt * 16 + l16) * 2048 + kt * 128 + kss * 32 + quad * 8);
        oacc[nt] = MFMA_BF16(pf, vf, oacc[nt]);
      }
    }
  }
  // epilogue: out = O / l -> Ao[(s*2+b)*1024 + h*64+e] (bf16)
  float linv[4];
#pragma unroll
  for (int r = 0; r < 4; ++r) {
    const float lr = __shfl(l_s, quad * 4 + r);
    linv[r] = 1.0f / lr;
  }
#pragma unroll
  for (int nt = 0; nt < 4; ++nt) {
    const int col = hh * 64 + nt * 16 + l16;
#pragma unroll
    for (int r = 0; r < 4; ++r) {
      const int srow = s0 + quad * 4 + r;
      Ao[(srow * 2 + bb) * 1024 + col] = f2b(oacc[nt][r] * linv[r]);
    }
  }
}

// ---------------------------------------------------------------------------
extern "C" void kernel_launch(void* const* d_in, const int* in_sizes, int n_in,
                              void* d_out, int out_size, void* d_ws, size_t ws_size,
                              hipStream_t stream) {
  const float* src = (const float*)d_in[0];
  const float* eb = (const float*)d_in[1];
  const float* wq = (const float*)d_in[2];
  const float* bq = (const float*)d_in[3];
  const float* wk = (const float*)d_in[4];
  const float* bk = (const float*)d_in[5];
  const float* wv = (const float*)d_in[6];
  const float* bv = (const float*)d_in[7];
  const float* wo = (const float*)d_in[8];
  const float* bo = (const float*)d_in[9];
  u16* ws = (u16*)d_ws;
  const size_t MM = 1024 * 1024;
  u16* wqT = ws;             // bf16 [N][K]
  u16* wkT = ws + MM;
  u16* wvT = ws + 2 * MM;
  u16* woT = ws + 3 * MM;
  u16* srcB = ws + 4 * MM;   // bf16 [4096][1024]
  u16* qW = ws + 8 * MM;     // bf16 [32][2048][64]
  u16* kW = ws + 12 * MM;    // bf16 [32][2048][64]
  u16* vW = ws + 16 * MM;    // bf16 [32][64][2048] (V^T)
  u16* aO = ws + 20 * MM;    // bf16 [4096][1024]
  float* out = (float*)d_out;

  convert_src<<<dim3(4096), 256, 0, stream>>>(src, srcB);
  transpose4<<<dim3(16, 16, 4), 256, 0, stream>>>(wq, wk, wv, wo, wqT, wkT, wvT, woT);
  gemm_bt<<<dim3(8, 32, 3), 256, 0, stream>>>(srcB, wqT, wkT, wvT, bq, bk, bv,
                                              qW, kW, vW, nullptr, 0);
  attn_fused<<<dim3(32, 32), 256, 0, stream>>>(qW, kW, vW, eb, aO);
  gemm_bt<<<dim3(8, 32, 1), 256, 0, stream>>>(aO, woT, woT, woT, bo, bo, bo,
                                              nullptr, nullptr, nullptr, out, 1);
}

// Round 6
// 341.964 us; speedup vs baseline: 1.3218x; 1.3218x over previous
//
#include <hip/hip_runtime.h>
#include <stdint.h>

typedef unsigned short u16;
typedef unsigned int u32;

typedef __bf16 bf8 __attribute__((ext_vector_type(8)));
typedef bf8 bf8a __attribute__((may_alias));
typedef float f32x4 __attribute__((ext_vector_type(4)));
typedef uint2 uint2a __attribute__((may_alias));
typedef ushort4 ushort4a __attribute__((may_alias));
typedef float4 float4a __attribute__((may_alias));

#define MFMA_BF16(a, b, c) __builtin_amdgcn_mfma_f32_16x16x32_bf16((a), (b), (c), 0, 0, 0)

__device__ __forceinline__ u16 f2b(float x) {
  u32 u = __float_as_uint(x);
  return (u16)((u + 0x7fffu + ((u >> 16) & 1u)) >> 16);  // RNE
}
__device__ __forceinline__ u32 pack2(float a, float b) {  // two non-negative f32 -> packed bf16x2
  u32 ua = __float_as_uint(a), ub = __float_as_uint(b);
  return ((ua + 0x8000u) >> 16) | ((ub + 0x8000u) & 0xffff0000u);
}
__device__ __forceinline__ void async16(const u16* g, void* l) {
  __builtin_amdgcn_global_load_lds((const __attribute__((address_space(1))) u32*)g,
                                   (__attribute__((address_space(3))) u32*)l, 16, 0, 0);
}

// ---------------------------------------------------------------------------
// src convert: fp32 [4096][1024] -> bf16 same layout. 1 float4 per thread.
// ---------------------------------------------------------------------------
__global__ __launch_bounds__(256) void convert_src(const float* __restrict__ src,
                                                   u16* __restrict__ dst) {
  const int i = blockIdx.x * 256 + threadIdx.x;  // float4 index
  float4 v = *(const float4a*)(src + i * 4);
  ushort4 o;
  o.x = f2b(v.x); o.y = f2b(v.y); o.z = f2b(v.z); o.w = f2b(v.w);
  *(ushort4a*)(dst + i * 4) = o;
}

// ---------------------------------------------------------------------------
// Weight transpose+convert: w fp32 [K=1024][N=1024] -> wT bf16 [N][K]
// ---------------------------------------------------------------------------
__global__ __launch_bounds__(256) void transpose4(
    const float* __restrict__ w0, const float* __restrict__ w1,
    const float* __restrict__ w2, const float* __restrict__ w3,
    u16* __restrict__ t0, u16* __restrict__ t1, u16* __restrict__ t2, u16* __restrict__ t3) {
  const int z = blockIdx.z;
  const float* W = z == 0 ? w0 : z == 1 ? w1 : z == 2 ? w2 : w3;
  u16* T = z == 0 ? t0 : z == 1 ? t1 : z == 2 ? t2 : t3;
  __shared__ __align__(8) u16 tile[64][68];
  const int tid = threadIdx.x;
  const int ty = tid >> 4, tx = tid & 15;
  const int kb = blockIdx.y * 64, nb = blockIdx.x * 64;
#pragma unroll
  for (int i = 0; i < 4; ++i) {
    int lk = ty + i * 16;
    float4 v = *(const float4a*)(W + (kb + lk) * 1024 + nb + tx * 4);
    ushort4 h;
    h.x = f2b(v.x); h.y = f2b(v.y); h.z = f2b(v.z); h.w = f2b(v.w);
    *(ushort4a*)&tile[lk][tx * 4] = h;
  }
  __syncthreads();
#pragma unroll
  for (int i = 0; i < 4; ++i) {
    int ln = ty + i * 16;
    ushort4 v;
    v.x = tile[tx * 4 + 0][ln];
    v.y = tile[tx * 4 + 1][ln];
    v.z = tile[tx * 4 + 2][ln];
    v.w = tile[tx * 4 + 3][ln];
    *(ushort4a*)(T + (nb + ln) * 1024 + kb + tx * 4) = v;
  }
}

// ---------------------------------------------------------------------------
// GEMM: C[M][N] = A[M,1024] * Bt[N,1024]^T + bias[n]   (m97 structure)
// (identical to round-3/5 passing version)
// ---------------------------------------------------------------------------
__global__ __launch_bounds__(256) void gemm_bt(
    const u16* __restrict__ A,
    const u16* __restrict__ B0, const u16* __restrict__ B1, const u16* __restrict__ B2,
    const float* __restrict__ c0, const float* __restrict__ c1, const float* __restrict__ c2,
    u16* __restrict__ O0, u16* __restrict__ O1, u16* __restrict__ O2,
    float* __restrict__ Of, int plain) {
  __shared__ __align__(16) u16 sm[8192];
  u16* As = sm;
  u16* Bs = sm + 4096;
  const int tid = threadIdx.x, lane = tid & 63, w = tid >> 6;
  const int wm = w >> 1, wn = w & 1, quad = lane >> 4, l16 = lane & 15;
  const int z = blockIdx.z;
  const u16* Bt = z == 0 ? B0 : (z == 1 ? B1 : B2);
  const float* bi = z == 0 ? c0 : (z == 1 ? c1 : c2);
  u16* O = z == 0 ? O0 : (z == 1 ? O1 : O2);
  const int row0 = blockIdx.y * 128, col0 = blockIdx.x * 128;

  f32x4 acc[4][4];
#pragma unroll
  for (int i = 0; i < 4; ++i)
#pragma unroll
    for (int j = 0; j < 4; ++j) acc[i][j] = f32x4{0.f, 0.f, 0.f, 0.f};

  const int e0 = tid, e1 = tid + 256;
  const int r0 = e0 >> 2, cc0 = (e0 & 3) * 8;
  const int r1 = e1 >> 2, cc1 = (e1 & 3) * 8;
  const u32 lb0 = (u32)(w * 64) * 16;
  const u32 lb1 = (u32)(w * 64 + 256) * 16;

  for (int k0 = 0; k0 < 1024; k0 += 32) {
    __syncthreads();
    async16(A + (row0 + r0) * 1024 + k0 + cc0, (char*)As + lb0);
    async16(A + (row0 + r1) * 1024 + k0 + cc1, (char*)As + lb1);
    async16(Bt + (col0 + r0) * 1024 + k0 + cc0, (char*)Bs + lb0);
    async16(Bt + (col0 + r1) * 1024 + k0 + cc1, (char*)Bs + lb1);
    __syncthreads();
    bf8a af[4], bfr[4];
#pragma unroll
    for (int i = 0; i < 4; ++i) {
      af[i] = *(const bf8a*)(As + (wm * 64 + i * 16 + l16) * 32 + quad * 8);
      bfr[i] = *(const bf8a*)(Bs + (wn * 64 + i * 16 + l16) * 32 + quad * 8);
    }
#pragma unroll
    for (int mt = 0; mt < 4; ++mt)
#pragma unroll
      for (int nt = 0; nt < 4; ++nt) acc[mt][nt] = MFMA_BF16(af[mt], bfr[nt], acc[mt][nt]);
  }

#pragma unroll
  for (int nt = 0; nt < 4; ++nt) {
    const int col = col0 + wn * 64 + nt * 16 + l16;
    const float bcol = bi[col];
#pragma unroll
    for (int mt = 0; mt < 4; ++mt) {
#pragma unroll
      for (int r = 0; r < 4; ++r) {
        const int rm = row0 + wm * 64 + mt * 16 + quad * 4 + r;
        const float fv = acc[mt][nt][r] + bcol;
        if (plain) {
          Of[rm * 1024 + col] = fv;
        } else {
          const u16 hv = f2b(fv);
          const int s = rm >> 1, b_ = rm & 1, hh = col >> 6, e = col & 63;
          const int p = b_ * 16 + hh;
          if (z < 2) O[(p * 2048 + s) * 64 + e] = hv;  // [pair][s][64]
          else O[(p * 64 + e) * 2048 + s] = hv;        // [pair][e][s] (V^T)
        }
      }
    }
  }
}

// ---------------------------------------------------------------------------
// Flash attention v6: split-t across waves. Block = 32 q-rows (2 s-tiles of
// 16, ALL waves share the same rows); wave w owns t-strip kt*128+w*32 each kt.
// Per wave: private partial (m, l, O) over its t-quarter; no barrier in the
// main loop. K/V global loads drop 4x vs v5 (each wave reads 1/4 of K/V).
// 2-barrier LDS merge epilogue combines the 4 partials (flash-decode merge).
// Per-wave softmax/P-LDS/PV mechanics verbatim from passing rounds 3/5.
// ---------------------------------------------------------------------------
__global__ __launch_bounds__(256, 4) void attn_fused(
    const u16* __restrict__ Qw, const u16* __restrict__ Kw, const u16* __restrict__ Vw,
    const float* __restrict__ EB, u16* __restrict__ Ao) {
  // LDS: [0,34816) = union{ per-wave P tiles (9216 B, main loop) | O-merge
  // partials float[4][32][68] (epilogue) }; [34816,35328) Mst f32[4][32];
  // [35328,35840) Lsc f32[4][32].
  __shared__ __align__(16) char smem[35840];
  const int tid = threadIdx.x, lane = tid & 63, w = tid >> 6;
  const int quad = lane >> 4, l16 = lane & 15;
  const int pair = blockIdx.x, qt = blockIdx.y;
  const int bb = pair >> 4, hh = pair & 15;
  const u16* Qp = Qw + pair * (2048 * 64);
  const u16* Kp = Kw + pair * (2048 * 64);
  const u16* Vp = Vw + pair * (64 * 2048);
  const int s0 = qt * 32;  // block's 32 q-rows (shared by all waves)
  // per-wave P region: [2 st][16 s][36 t] u16 (pad 36 breaks bank aliasing)
  u16* const Pw = (u16*)smem + w * (2 * 16 * 36);
  float* const Olds = (float*)smem;              // [4][32][68]
  float* const Mst = (float*)(smem + 34816);     // [4][32]
  float* const Lsc = (float*)(smem + 35328);     // [4][32]

  bf8a qf[2][2];  // B-operand (Q^T): [st][ks]; n=s, k=d
#pragma unroll
  for (int st = 0; st < 2; ++st)
#pragma unroll
    for (int ks = 0; ks < 2; ++ks)
      qf[st][ks] = *(const bf8a*)(Qp + (s0 + st * 16 + l16) * 64 + ks * 32 + quad * 8);

  f32x4 oacc[2][4];
#pragma unroll
  for (int i = 0; i < 2; ++i)
#pragma unroll
    for (int j = 0; j < 4; ++j) oacc[i][j] = f32x4{0.f, 0.f, 0.f, 0.f};
  float m_s[2] = {-1e30f, -1e30f};
  float l_s[2] = {0.f, 0.f};
  const float c1 = 0.125f * 1.44269504088896340736f;  // scale * log2(e)
  const float c2 = 1.44269504088896340736f;

  for (int kt = 0; kt < 16; ++kt) {
    const int tbase = kt * 128 + w * 32;  // wave's 32-t strip
    // --- issue all independent global loads up front (latency overlap) ---
    bf8a kf[2][2];  // K A-operand rows t: [tt][ks]
#pragma unroll
    for (int tt = 0; tt < 2; ++tt) {
      const u16* kr = Kp + (tbase + tt * 16 + l16) * 64 + quad * 8;
      kf[tt][0] = *(const bf8a*)kr;
      kf[tt][1] = *(const bf8a*)(kr + 32);
    }
    bf8a vf[4];  // V^T rows e: [nt], k=t strip
#pragma unroll
    for (int nt = 0; nt < 4; ++nt)
      vf[nt] = *(const bf8a*)(Vp + (nt * 16 + l16) * 2048 + tbase + quad * 8);
    float4 bw[2][2];  // EB [st][tt]: row s, cols tbase + tt*16 + quad*4
#pragma unroll
    for (int st = 0; st < 2; ++st)
#pragma unroll
      for (int tt = 0; tt < 2; ++tt)
        bw[st][tt] = *(const float4a*)(EB + (s0 + st * 16 + l16) * 2048 + tbase + tt * 16 + quad * 4);

    // --- S^T = K * Q^T : D[row=t][col=s] ---
    f32x4 sacc[2][2];  // [tt][st]
#pragma unroll
    for (int tt = 0; tt < 2; ++tt)
#pragma unroll
      for (int st = 0; st < 2; ++st) {
        f32x4 t0 = f32x4{0.f, 0.f, 0.f, 0.f};
        t0 = MFMA_BF16(kf[tt][0], qf[st][0], t0);
        sacc[tt][st] = MFMA_BF16(kf[tt][1], qf[st][1], t0);
      }
    // --- z = qk*c1 + bias*c2; sign masks; per-st online softmax ---
    u32 sg01[2][2], sg23[2][2];
#pragma unroll
    for (int tt = 0; tt < 2; ++tt)
#pragma unroll
      for (int st = 0; st < 2; ++st) {
        const float4 b = bw[st][tt];
        sacc[tt][st][0] = sacc[tt][st][0] * c1 + b.x * c2;
        sacc[tt][st][1] = sacc[tt][st][1] * c1 + b.y * c2;
        sacc[tt][st][2] = sacc[tt][st][2] * c1 + b.z * c2;
        sacc[tt][st][3] = sacc[tt][st][3] * c1 + b.w * c2;
        sg01[tt][st] = ((__float_as_uint(b.x) >> 16) & 0x8000u) | (__float_as_uint(b.y) & 0x80000000u);
        sg23[tt][st] = ((__float_as_uint(b.z) >> 16) & 0x8000u) | (__float_as_uint(b.w) & 0x80000000u);
      }
    float alpha[2];
#pragma unroll
    for (int st = 0; st < 2; ++st) {
      float m = fmaxf(fmaxf(fmaxf(sacc[0][st][0], sacc[0][st][1]),
                            fmaxf(sacc[0][st][2], sacc[0][st][3])),
                      fmaxf(fmaxf(sacc[1][st][0], sacc[1][st][1]),
                            fmaxf(sacc[1][st][2], sacc[1][st][3])));
      m = fmaxf(m, __shfl_xor(m, 16));
      m = fmaxf(m, __shfl_xor(m, 32));
      const float mn = fmaxf(m_s[st], m);
      alpha[st] = exp2f(m_s[st] - mn);
      m_s[st] = mn;
    }
    // --- p = exp2(z-m), pack with sign gate, l update ---
#pragma unroll
    for (int st = 0; st < 2; ++st) {
      float lsum = 0.f;
#pragma unroll
      for (int tt = 0; tt < 2; ++tt) {
        const float p0 = exp2f(sacc[tt][st][0] - m_s[st]);
        const float p1 = exp2f(sacc[tt][st][1] - m_s[st]);
        const float p2 = exp2f(sacc[tt][st][2] - m_s[st]);
        const float p3 = exp2f(sacc[tt][st][3] - m_s[st]);
        lsum += (p0 + p1) + (p2 + p3);
        uint2 v;
        v.x = pack2(p0, p1) | sg01[tt][st];
        v.y = pack2(p2, p3) | sg23[tt][st];
        // P write: (s=l16, t = tt*16 + quad*4 + [0,4)) -> Pw[st][l16][t]
        *(uint2a*)((char*)Pw + st * (16 * 36 * 2) + l16 * 72 + tt * 32 + quad * 8) = v;
      }
      lsum += __shfl_xor(lsum, 16);
      lsum += __shfl_xor(lsum, 32);
      l_s[st] = l_s[st] * alpha[st] + lsum;
    }
    // --- O *= alpha; PV: A = P (1 b128/st), B = vf ---
#pragma unroll
    for (int st = 0; st < 2; ++st) {
      float ar[4];
#pragma unroll
      for (int r = 0; r < 4; ++r) ar[r] = __shfl(alpha[st], quad * 4 + r);
#pragma unroll
      for (int nt = 0; nt < 4; ++nt)
#pragma unroll
        for (int r = 0; r < 4; ++r) oacc[st][nt][r] *= ar[r];
      bf8a pf = *(const bf8a*)((char*)Pw + st * (16 * 36 * 2) + l16 * 72 + quad * 16);
#pragma unroll
      for (int nt = 0; nt < 4; ++nt) oacc[st][nt] = MFMA_BF16(pf, vf[nt], oacc[st][nt]);
    }
  }

  // ---------------- merge epilogue (2 barriers) ----------------
  // stats out (m uniform across quads)
  if (quad == 0) {
#pragma unroll
    for (int st = 0; st < 2; ++st) Mst[w * 32 + st * 16 + l16] = m_s[st];
  }
  __syncthreads();
  // each wave: global M per row, beta = exp2(m_w - M), scale own O, stash
#pragma unroll
  for (int st = 0; st < 2; ++st) {
    const int row = st * 16 + l16;
    float M = fmaxf(fmaxf(Mst[row], Mst[32 + row]), fmaxf(Mst[64 + row], Mst[96 + row]));
    const float beta = exp2f(m_s[st] - M);
    if (quad == 0) Lsc[w * 32 + row] = beta * l_s[st];
    float br[4];
#pragma unroll
    for (int r = 0; r < 4; ++r) br[r] = __shfl(beta, quad * 4 + r);
#pragma unroll
    for (int nt = 0; nt < 4; ++nt)
#pragma unroll
      for (int r = 0; r < 4; ++r) {
        Olds[w * 2176 + (st * 16 + quad * 4 + r) * 68 + nt * 16 + l16] = oacc[st][nt][r] * br[r];
      }
  }
  __syncthreads();
  // final: wave w -> rows [w*8, w*8+8); lane: row = lane>>3, e0 = (lane&7)*8
  {
    const int rl = w * 8 + (lane >> 3);
    const int e0i = (lane & 7) * 8;
    float a[8];
#pragma unroll
    for (int j = 0; j < 8; ++j) a[j] = 0.f;
#pragma unroll
    for (int wp = 0; wp < 4; ++wp) {
      const float* p = Olds + wp * 2176 + rl * 68 + e0i;
      const float4 x = *(const float4a*)p;
      const float4 y = *(const float4a*)(p + 4);
      a[0] += x.x; a[1] += x.y; a[2] += x.z; a[3] += x.w;
      a[4] += y.x; a[5] += y.y; a[6] += y.z; a[7] += y.w;
    }
    const float lt = Lsc[rl] + Lsc[32 + rl] + Lsc[64 + rl] + Lsc[96 + rl];
    const float inv = 1.0f / lt;
    ushort4 o0, o1;
    o0.x = f2b(a[0] * inv); o0.y = f2b(a[1] * inv); o0.z = f2b(a[2] * inv); o0.w = f2b(a[3] * inv);
    o1.x = f2b(a[4] * inv); o1.y = f2b(a[5] * inv); o1.z = f2b(a[6] * inv); o1.w = f2b(a[7] * inv);
    u16* dst = Ao + ((s0 + rl) * 2 + bb) * 1024 + hh * 64 + e0i;
    *(ushort4a*)dst = o0;
    *(ushort4a*)(dst + 4) = o1;
  }
}

// ---------------------------------------------------------------------------
extern "C" void kernel_launch(void* const* d_in, const int* in_sizes, int n_in,
                              void* d_out, int out_size, void* d_ws, size_t ws_size,
                              hipStream_t stream) {
  const float* src = (const float*)d_in[0];
  const float* eb = (const float*)d_in[1];
  const float* wq = (const float*)d_in[2];
  const float* bq = (const float*)d_in[3];
  const float* wk = (const float*)d_in[4];
  const float* bk = (const float*)d_in[5];
  const float* wv = (const float*)d_in[6];
  const float* bv = (const float*)d_in[7];
  const float* wo = (const float*)d_in[8];
  const float* bo = (const float*)d_in[9];
  u16* ws = (u16*)d_ws;
  const size_t MM = 1024 * 1024;
  u16* wqT = ws;             // bf16 [N][K]
  u16* wkT = ws + MM;
  u16* wvT = ws + 2 * MM;
  u16* woT = ws + 3 * MM;
  u16* srcB = ws + 4 * MM;   // bf16 [4096][1024]
  u16* qW = ws + 8 * MM;     // bf16 [32][2048][64]
  u16* kW = ws + 12 * MM;    // bf16 [32][2048][64]
  u16* vW = ws + 16 * MM;    // bf16 [32][64][2048] (V^T)
  u16* aO = ws + 20 * MM;    // bf16 [4096][1024]
  float* out = (float*)d_out;

  convert_src<<<dim3(4096), 256, 0, stream>>>(src, srcB);
  transpose4<<<dim3(16, 16, 4), 256, 0, stream>>>(wq, wk, wv, wo, wqT, wkT, wvT, woT);
  gemm_bt<<<dim3(8, 32, 3), 256, 0, stream>>>(srcB, wqT, wkT, wvT, bq, bk, bv,
                                              qW, kW, vW, nullptr, 0);
  attn_fused<<<dim3(32, 64), 256, 0, stream>>>(qW, kW, vW, eb, aO);
  gemm_bt<<<dim3(8, 32, 1), 256, 0, stream>>>(aO, woT, woT, woT, bo, bo, bo,
                                              nullptr, nullptr, nullptr, out, 1);
}